// Round 1
// baseline (1183.807 us; speedup 1.0000x reference)
//
#include <hip/hip_runtime.h>

#define N_NODES 100000
#define N_EDGES 600000
#define DIM 128
#define SCAN_B 1024
#define NCHUNK 98   // ceil(100000/1024)

typedef __attribute__((ext_vector_type(4))) float f32x4;
typedef __attribute__((ext_vector_type(8))) short bf16x8;

__device__ __forceinline__ short f2bf(float f) {
    union { float f; unsigned u; } cv; cv.f = f;
    unsigned r = (cv.u + 0x7FFFu + ((cv.u >> 16) & 1u)) >> 16;
    return (short)r;
}

// ---------------- setup: degree / scan / csr fill / weight pack ----------------

__global__ void k_degree(const int* __restrict__ src, int* __restrict__ degi) {
    int e = blockIdx.x * 256 + threadIdx.x;
    if (e < N_EDGES) atomicAdd(&degi[src[e]], 1);
}

__global__ void k_chunksum(const int* __restrict__ degi, int* __restrict__ bsum) {
    __shared__ int sm[SCAN_B];
    int i = blockIdx.x * SCAN_B + threadIdx.x;
    sm[threadIdx.x] = (i < N_NODES) ? degi[i] : 0;
    __syncthreads();
    for (int s = SCAN_B / 2; s > 0; s >>= 1) {
        if (threadIdx.x < (unsigned)s) sm[threadIdx.x] += sm[threadIdx.x + s];
        __syncthreads();
    }
    if (threadIdx.x == 0) bsum[blockIdx.x] = sm[0];
}

__global__ void k_scanb(int* __restrict__ bsum, int nb) {
    __shared__ int sm[128];
    int t = threadIdx.x;
    int v = (t < nb) ? bsum[t] : 0;
    sm[t] = v; __syncthreads();
    for (int s = 1; s < 128; s <<= 1) {
        int a = (t >= s) ? sm[t - s] : 0;
        __syncthreads();
        sm[t] += a;
        __syncthreads();
    }
    if (t < nb) bsum[t] = sm[t] - v;  // exclusive
}

__global__ void k_rowptr(const int* __restrict__ degi, const int* __restrict__ bsum,
                         int* __restrict__ rowptr, int* __restrict__ cnt,
                         float* __restrict__ inv0, float* __restrict__ inv1,
                         float* __restrict__ inv2) {
    __shared__ int sm[SCAN_B];
    int i = blockIdx.x * SCAN_B + threadIdx.x;
    int v = (i < N_NODES) ? degi[i] : 0;
    sm[threadIdx.x] = v; __syncthreads();
    for (int s = 1; s < SCAN_B; s <<= 1) {
        int a = (threadIdx.x >= (unsigned)s) ? sm[threadIdx.x - s] : 0;
        __syncthreads();
        sm[threadIdx.x] += a;
        __syncthreads();
    }
    if (i < N_NODES) {
        int excl = bsum[blockIdx.x] + sm[threadIdx.x] - v;
        rowptr[i] = excl;
        cnt[i] = excl;
        float d = (float)v;
        inv0[i] = (v > 0) ? 1.0f / d : 0.0f;
        inv1[i] = 1.0f / (d + 1.0f);
        inv2[i] = 1.0f / (d + 2.0f);
    }
}

__global__ void k_fill(const int* __restrict__ src, const int* __restrict__ dst,
                       int* __restrict__ cnt, int* __restrict__ col) {
    int e = blockIdx.x * 256 + threadIdx.x;
    if (e < N_EDGES) {
        int pos = atomicAdd(&cnt[src[e]], 1);
        col[pos] = dst[e];
    }
}

// Wpack[l][kb(8)][nt(16)][lane(64)][j(8)]  = W[k][n], k=kb*32+(lane>>4)*8+j, n=nt*16+(lane&15)
// W[k][n] for n<128: k<128 ? G1[n][k] : G2[n][k-128]  (gamma); n>=128: same with B1/B2 (beta)
__global__ void k_pack(const float* __restrict__ G1, const float* __restrict__ G2,
                       const float* __restrict__ B1, const float* __restrict__ B2,
                       short* __restrict__ Wp) {
    int idx = blockIdx.x * 256 + threadIdx.x;  // 3*65536 = 196608 total
    int j = idx & 7, lane = (idx >> 3) & 63, nt = (idx >> 9) & 15, kb = (idx >> 13) & 7, l = idx >> 16;
    int k = kb * 32 + (lane >> 4) * 8 + j;
    int n = nt * 16 + (lane & 15);
    float v;
    if (n < 128) {
        v = (k < 128) ? G1[(l * 128 + n) * 128 + k] : G2[(l * 128 + n) * 128 + (k - 128)];
    } else {
        int n2 = n - 128;
        v = (k < 128) ? B1[(l * 128 + n2) * 128 + k] : B2[(l * 128 + n2) * 128 + (k - 128)];
    }
    Wp[idx] = f2bf(v);
}

// ---------------- aggregation kernels (1 wave per row, 4 waves/block) ----------------

// head: fused  h_next = inv1*(S+h);  emb (+)= h_next  (emb lives in d_out, scaled at last hop)
__global__ __launch_bounds__(256) void k_agg_head(
    const float* __restrict__ h_cur, float* __restrict__ h_next,
    float* emb, const float* __restrict__ inv1,
    const int* __restrict__ rowptr, const int* __restrict__ degi,
    const int* __restrict__ col, int init, int store_next, float scale)
{
    int row = (blockIdx.x * 256 + threadIdx.x) >> 6;
    if (row >= N_NODES) return;
    int lane = threadIdx.x & 63;
    int start = rowptr[row];
    int d = degi[row];
    const float2* h2 = (const float2*)h_cur;
    float ax = 0.f, ay = 0.f;
    for (int e = 0; e < d; ++e) {
        int c = col[start + e];
        float2 v = h2[c * 64 + lane];
        ax += v.x; ay += v.y;
    }
    float2 hv = h2[row * 64 + lane];
    float w = inv1[row];
    float hnx = w * (ax + hv.x);
    float hny = w * (ay + hv.y);
    if (store_next) {
        float2 o; o.x = hnx; o.y = hny;
        ((float2*)h_next)[row * 64 + lane] = o;
    }
    float2 ep;
    if (init) ep = hv;  // hop 0: h_cur == x
    else ep = ((float2*)emb)[row * 64 + lane];
    float2 eo; eo.x = scale * (ep.x + hnx); eo.y = scale * (ep.y + hny);
    ((float2*)emb)[row * 64 + lane] = eo;
}

// tail: raw row-sum only (update handled by the GEMM kernel)
__global__ __launch_bounds__(256) void k_agg_tail(
    const float* __restrict__ h_cur, float* __restrict__ S,
    const int* __restrict__ rowptr, const int* __restrict__ degi,
    const int* __restrict__ col)
{
    int row = (blockIdx.x * 256 + threadIdx.x) >> 6;
    if (row >= N_NODES) return;
    int lane = threadIdx.x & 63;
    int start = rowptr[row];
    int d = degi[row];
    const float2* h2 = (const float2*)h_cur;
    float ax = 0.f, ay = 0.f;
    for (int e = 0; e < d; ++e) {
        int c = col[start + e];
        float2 v = h2[c * 64 + lane];
        ax += v.x; ay += v.y;
    }
    float2 o; o.x = ax; o.y = ay;
    ((float2*)S)[row * 64 + lane] = o;
}

// ---------------- tail GEMM + update (MFMA bf16 16x16x32) ----------------
// Z = [h | inv0*S] @ Wl  (N x 256), Z1 = cols 0..127, Z2 = cols 128..255
// gamma = lrelu(Z1)+1; beta = lrelu(Z2); m = h + gamma*R + beta - inv0*S
// h_new = inv2*(S + h + m) written in-place over S; emb accumulated.
// Each wave: 32 rows x 256 cols (two 16-row A frags, 16 col tiles x2). Block = 4 waves = 128 rows.
__global__ __launch_bounds__(256) void k_gemm_tail(
    const float* __restrict__ h_cur, float* S,
    const float* emb_in, float* emb_out,
    const float* __restrict__ Rl, const short* __restrict__ Wp,
    const float* __restrict__ inv0, const float* __restrict__ inv2,
    const int* __restrict__ degi, int init, int last)
{
    int wave = threadIdx.x >> 6;
    int lane = threadIdx.x & 63;
    int quad = lane >> 4;
    int m16 = lane & 15;
    int r0 = blockIdx.x * 128 + wave * 32;

    int rowA0 = r0 + m16;
    int rowA1 = r0 + 16 + m16;
    int cA0 = rowA0 < N_NODES ? rowA0 : N_NODES - 1;
    int cA1 = rowA1 < N_NODES ? rowA1 : N_NODES - 1;
    float w0a = inv0[cA0];
    float w0b = inv0[cA1];

    f32x4 acc0[16], acc1[16];
    const f32x4 vzero = {0.f, 0.f, 0.f, 0.f};
#pragma unroll
    for (int t = 0; t < 16; ++t) { acc0[t] = vzero; acc1[t] = vzero; }

#pragma unroll
    for (int kb = 0; kb < 8; ++kb) {
        int kk = kb * 32 + quad * 8;
        bf16x8 a0, a1;
        if (kb < 4) {
            float4 u0 = *(const float4*)(h_cur + (size_t)cA0 * DIM + kk);
            float4 u1 = *(const float4*)(h_cur + (size_t)cA0 * DIM + kk + 4);
            float4 v0 = *(const float4*)(h_cur + (size_t)cA1 * DIM + kk);
            float4 v1 = *(const float4*)(h_cur + (size_t)cA1 * DIM + kk + 4);
            a0[0]=f2bf(u0.x); a0[1]=f2bf(u0.y); a0[2]=f2bf(u0.z); a0[3]=f2bf(u0.w);
            a0[4]=f2bf(u1.x); a0[5]=f2bf(u1.y); a0[6]=f2bf(u1.z); a0[7]=f2bf(u1.w);
            a1[0]=f2bf(v0.x); a1[1]=f2bf(v0.y); a1[2]=f2bf(v0.z); a1[3]=f2bf(v0.w);
            a1[4]=f2bf(v1.x); a1[5]=f2bf(v1.y); a1[6]=f2bf(v1.z); a1[7]=f2bf(v1.w);
        } else {
            int kk2 = kk - 128;
            float4 u0 = *(const float4*)(S + (size_t)cA0 * DIM + kk2);
            float4 u1 = *(const float4*)(S + (size_t)cA0 * DIM + kk2 + 4);
            float4 v0 = *(const float4*)(S + (size_t)cA1 * DIM + kk2);
            float4 v1 = *(const float4*)(S + (size_t)cA1 * DIM + kk2 + 4);
            a0[0]=f2bf(w0a*u0.x); a0[1]=f2bf(w0a*u0.y); a0[2]=f2bf(w0a*u0.z); a0[3]=f2bf(w0a*u0.w);
            a0[4]=f2bf(w0a*u1.x); a0[5]=f2bf(w0a*u1.y); a0[6]=f2bf(w0a*u1.z); a0[7]=f2bf(w0a*u1.w);
            a1[0]=f2bf(w0b*v0.x); a1[1]=f2bf(w0b*v0.y); a1[2]=f2bf(w0b*v0.z); a1[3]=f2bf(w0b*v0.w);
            a1[4]=f2bf(w0b*v1.x); a1[5]=f2bf(w0b*v1.y); a1[6]=f2bf(w0b*v1.z); a1[7]=f2bf(w0b*v1.w);
        }
        const short* wb = Wp + kb * 8192 + lane * 8;
#pragma unroll
        for (int nt = 0; nt < 16; ++nt) {
            bf16x8 b = *(const bf16x8*)(wb + nt * 512);
            acc0[nt] = __builtin_amdgcn_mfma_f32_16x16x32_bf16(a0, b, acc0[nt], 0, 0, 0);
            acc1[nt] = __builtin_amdgcn_mfma_f32_16x16x32_bf16(a1, b, acc1[nt], 0, 0, 0);
        }
    }

    // epilogue: C/D layout col = lane&15, row = quad*4 + reg
#pragma unroll
    for (int t = 0; t < 2; ++t) {
        const f32x4* accp = t ? acc1 : acc0;
        int ibase = r0 + t * 16 + quad * 4;
#pragma unroll
        for (int r = 0; r < 4; ++r) {
            int i = ibase + r;
            if (i < N_NODES) {
                float wi0 = inv0[i];
                float wi2 = inv2[i];
                size_t rowoff = (size_t)i * DIM + m16;
#pragma unroll
                for (int nt = 0; nt < 8; ++nt) {
                    size_t o = rowoff + nt * 16;
                    float z1 = accp[nt][r];
                    float z2 = accp[nt + 8][r];
                    float hval = h_cur[o];
                    float sval = S[o];
                    float nbv = wi0 * sval;
                    float gamma = (z1 > 0.f ? z1 : 0.2f * z1) + 1.0f;
                    float beta  = (z2 > 0.f ? z2 : 0.2f * z2);
                    float mm = hval + gamma * Rl[nt * 16 + m16] + beta - nbv;
                    float hn = wi2 * (sval + hval + mm);
                    float ev = (init ? hval : emb_in[o]) + hn;
                    if (last) {
                        if (degi[i] <= 5) emb_out[o] = 0.25f * ev;
                    } else {
                        S[o] = hn;          // in-place h_next (row-disjoint across blocks)
                        emb_out[o] = ev;
                    }
                }
            }
        }
    }
}

// ---------------- launch ----------------

extern "C" void kernel_launch(void* const* d_in, const int* in_sizes, int n_in,
                              void* d_out, int out_size, void* d_ws, size_t ws_size,
                              hipStream_t stream) {
    const float* x  = (const float*)d_in[0];
    const float* G1 = (const float*)d_in[1];
    const float* G2 = (const float*)d_in[2];
    const float* B1 = (const float*)d_in[3];
    const float* B2 = (const float*)d_in[4];
    const float* R  = (const float*)d_in[5];
    const int* esrc = (const int*)d_in[6];
    const int* edst = (const int*)d_in[7];
    float* out = (float*)d_out;

    char* base = (char*)d_ws;
    size_t off = 0;
    auto alloc = [&](size_t b) -> void* {
        void* p = base + off;
        off = (off + b + 255) & ~(size_t)255;
        return p;
    };
    int* degi     = (int*)alloc(4 * N_NODES);
    int* rowptr   = (int*)alloc(4 * N_NODES);
    int* cnt      = (int*)alloc(4 * N_NODES);
    int* bsum     = (int*)alloc(4 * 256);
    int* col      = (int*)alloc(4 * N_EDGES);
    float* inv0   = (float*)alloc(4 * N_NODES);
    float* inv1   = (float*)alloc(4 * N_NODES);
    float* inv2   = (float*)alloc(4 * N_NODES);
    short* Wp     = (short*)alloc(2 * 3 * 65536);
    float* bufA   = (float*)alloc(4ull * N_NODES * DIM);
    float* bufB   = (float*)alloc(4ull * N_NODES * DIM);
    float* embT   = (float*)alloc(4ull * N_NODES * DIM);

    hipMemsetAsync(degi, 0, 4 * N_NODES, stream);
    k_degree<<<(N_EDGES + 255) / 256, 256, 0, stream>>>(esrc, degi);
    k_chunksum<<<NCHUNK, SCAN_B, 0, stream>>>(degi, bsum);
    k_scanb<<<1, 128, 0, stream>>>(bsum, NCHUNK);
    k_rowptr<<<NCHUNK, SCAN_B, 0, stream>>>(degi, bsum, rowptr, cnt, inv0, inv1, inv2);
    k_fill<<<(N_EDGES + 255) / 256, 256, 0, stream>>>(esrc, edst, cnt, col);
    k_pack<<<768, 256, 0, stream>>>(G1, G2, B1, B2, Wp);

    // ---- head pass (emb accumulates directly in d_out; no GEMMs needed) ----
    k_agg_head<<<25000, 256, 0, stream>>>(x,    bufA, out, inv1, rowptr, degi, col, 1, 1, 1.0f);
    k_agg_head<<<25000, 256, 0, stream>>>(bufA, bufB, out, inv1, rowptr, degi, col, 0, 1, 1.0f);
    k_agg_head<<<25000, 256, 0, stream>>>(bufB, bufA, out, inv1, rowptr, degi, col, 0, 0, 0.25f);

    // ---- tail pass (agg -> GEMM+update per hop; h_next in-place over S) ----
    k_agg_tail<<<25000, 256, 0, stream>>>(x, bufA, rowptr, degi, col);
    k_gemm_tail<<<782, 256, 0, stream>>>(x,    bufA, embT, embT, R,       Wp,           inv0, inv2, degi, 1, 0);
    k_agg_tail<<<25000, 256, 0, stream>>>(bufA, bufB, rowptr, degi, col);
    k_gemm_tail<<<782, 256, 0, stream>>>(bufA, bufB, embT, embT, R + 128, Wp + 65536,   inv0, inv2, degi, 0, 0);
    k_agg_tail<<<25000, 256, 0, stream>>>(bufB, bufA, rowptr, degi, col);
    k_gemm_tail<<<782, 256, 0, stream>>>(bufB, bufA, embT, out,  R + 256, Wp + 131072,  inv0, inv2, degi, 0, 1);
}

// Round 2
// 599.091 us; speedup vs baseline: 1.9760x; 1.9760x over previous
//
#include <hip/hip_runtime.h>

#define N_NODES 100000
#define N_EDGES 600000
#define DIM 128
#define SCAN_B 1024
#define NCHUNK 98   // ceil(100000/1024)

typedef __attribute__((ext_vector_type(4))) float f32x4;
typedef __attribute__((ext_vector_type(8))) short bf16x8;
typedef __attribute__((ext_vector_type(4))) unsigned short u16x4;

__device__ __forceinline__ unsigned short f2bf(float f) {
    union { float f; unsigned u; } cv; cv.f = f;
    unsigned r = (cv.u + 0x7FFFu + ((cv.u >> 16) & 1u)) >> 16;
    return (unsigned short)r;
}
__device__ __forceinline__ float bflo(unsigned v) {
    union { unsigned u; float f; } c; c.u = v << 16; return c.f;
}
__device__ __forceinline__ float bfhi(unsigned v) {
    union { unsigned u; float f; } c; c.u = v & 0xFFFF0000u; return c.f;
}
__device__ __forceinline__ float bf2f(unsigned short v) {
    union { unsigned u; float f; } c; c.u = ((unsigned)v) << 16; return c.f;
}

// ---------------- setup: degree / scan / csr fill / weight pack ----------------

__global__ void k_degree(const int* __restrict__ src, int* __restrict__ degi) {
    int e = blockIdx.x * 256 + threadIdx.x;
    if (e < N_EDGES) atomicAdd(&degi[src[e]], 1);
}

__global__ void k_chunksum(const int* __restrict__ degi, int* __restrict__ bsum) {
    __shared__ int sm[SCAN_B];
    int i = blockIdx.x * SCAN_B + threadIdx.x;
    sm[threadIdx.x] = (i < N_NODES) ? degi[i] : 0;
    __syncthreads();
    for (int s = SCAN_B / 2; s > 0; s >>= 1) {
        if (threadIdx.x < (unsigned)s) sm[threadIdx.x] += sm[threadIdx.x + s];
        __syncthreads();
    }
    if (threadIdx.x == 0) bsum[blockIdx.x] = sm[0];
}

__global__ void k_scanb(int* __restrict__ bsum, int nb) {
    __shared__ int sm[128];
    int t = threadIdx.x;
    int v = (t < nb) ? bsum[t] : 0;
    sm[t] = v; __syncthreads();
    for (int s = 1; s < 128; s <<= 1) {
        int a = (t >= s) ? sm[t - s] : 0;
        __syncthreads();
        sm[t] += a;
        __syncthreads();
    }
    if (t < nb) bsum[t] = sm[t] - v;  // exclusive
}

__global__ void k_rowptr(const int* __restrict__ degi, const int* __restrict__ bsum,
                         int* __restrict__ rowptr, int* __restrict__ cnt,
                         float* __restrict__ inv0, float* __restrict__ inv1,
                         float* __restrict__ inv2) {
    __shared__ int sm[SCAN_B];
    int i = blockIdx.x * SCAN_B + threadIdx.x;
    int v = (i < N_NODES) ? degi[i] : 0;
    sm[threadIdx.x] = v; __syncthreads();
    for (int s = 1; s < SCAN_B; s <<= 1) {
        int a = (threadIdx.x >= (unsigned)s) ? sm[threadIdx.x - s] : 0;
        __syncthreads();
        sm[threadIdx.x] += a;
        __syncthreads();
    }
    if (i < N_NODES) {
        int excl = bsum[blockIdx.x] + sm[threadIdx.x] - v;
        rowptr[i] = excl;
        cnt[i] = excl;
        float d = (float)v;
        inv0[i] = (v > 0) ? 1.0f / d : 0.0f;
        inv1[i] = 1.0f / (d + 1.0f);
        inv2[i] = 1.0f / (d + 2.0f);
    }
}

__global__ void k_fill(const int* __restrict__ src, const int* __restrict__ dst,
                       int* __restrict__ cnt, int* __restrict__ col) {
    int e = blockIdx.x * 256 + threadIdx.x;
    if (e < N_EDGES) {
        int pos = atomicAdd(&cnt[src[e]], 1);
        col[pos] = dst[e];
    }
}

// Wpack[l][kb(8)][nt(16)][lane(64)][j(8)]  = W[k][n], k=kb*32+(lane>>4)*8+j, n=nt*16+(lane&15)
__global__ void k_pack(const float* __restrict__ G1, const float* __restrict__ G2,
                       const float* __restrict__ B1, const float* __restrict__ B2,
                       short* __restrict__ Wp) {
    int idx = blockIdx.x * 256 + threadIdx.x;  // 3*65536 = 196608 total
    int j = idx & 7, lane = (idx >> 3) & 63, nt = (idx >> 9) & 15, kb = (idx >> 13) & 7, l = idx >> 16;
    int k = kb * 32 + (lane >> 4) * 8 + j;
    int n = nt * 16 + (lane & 15);
    float v;
    if (n < 128) {
        v = (k < 128) ? G1[(l * 128 + n) * 128 + k] : G2[(l * 128 + n) * 128 + (k - 128)];
    } else {
        int n2 = n - 128;
        v = (k < 128) ? B1[(l * 128 + n2) * 128 + k] : B2[(l * 128 + n2) * 128 + (k - 128)];
    }
    Wp[idx] = (short)f2bf(v);
}

__global__ void k_xcast(const float* __restrict__ x, unsigned short* __restrict__ xb) {
    int i = (blockIdx.x * 256 + threadIdx.x) * 4;
    f32x4 v = *(const f32x4*)(x + i);
    u16x4 o; o[0] = f2bf(v[0]); o[1] = f2bf(v[1]); o[2] = f2bf(v[2]); o[3] = f2bf(v[3]);
    *(u16x4*)(xb + i) = o;
}

// ---------------- aggregation (1 wave/row, bf16 gather, shfl-broadcast cols) ----------------

__device__ __forceinline__ void gather_row(const unsigned* __restrict__ h2,
        const int* __restrict__ col, int start, int d, int lane,
        float& ax, float& ay) {
    ax = 0.f; ay = 0.f;
    int dd = d < 64 ? d : 64;
    int idx = (lane < dd) ? col[start + lane] : 0;
    int e = 0;
    for (; e + 4 <= dd; e += 4) {
        int c0 = __shfl(idx, e, 64);
        int c1 = __shfl(idx, e + 1, 64);
        int c2 = __shfl(idx, e + 2, 64);
        int c3 = __shfl(idx, e + 3, 64);
        unsigned v0 = h2[(size_t)c0 * 64 + lane];
        unsigned v1 = h2[(size_t)c1 * 64 + lane];
        unsigned v2 = h2[(size_t)c2 * 64 + lane];
        unsigned v3 = h2[(size_t)c3 * 64 + lane];
        ax += bflo(v0) + bflo(v1) + bflo(v2) + bflo(v3);
        ay += bfhi(v0) + bfhi(v1) + bfhi(v2) + bfhi(v3);
    }
    for (; e < dd; ++e) {
        int c = __shfl(idx, e, 64);
        unsigned v = h2[(size_t)c * 64 + lane];
        ax += bflo(v); ay += bfhi(v);
    }
    for (; e < d; ++e) {  // cold path: deg > 64 (practically never)
        int c = col[start + e];
        unsigned v = h2[(size_t)c * 64 + lane];
        ax += bflo(v); ay += bfhi(v);
    }
}

// head: h_next = inv1*(S + h_self); final hop computes emb = 0.25*(x+h1+h2+h3) -> out (ALL rows)
__global__ __launch_bounds__(256) void k_agg_head(
    const unsigned short* __restrict__ hsrc, unsigned short* __restrict__ hnext,
    const unsigned short* __restrict__ xb, const unsigned short* __restrict__ h1b,
    float* __restrict__ outp, const float* __restrict__ inv1,
    const int* __restrict__ rowptr, const int* __restrict__ degi,
    const int* __restrict__ col, int final_hop)
{
    int row = (blockIdx.x * 256 + threadIdx.x) >> 6;
    if (row >= N_NODES) return;
    int lane = threadIdx.x & 63;
    const unsigned* h2 = (const unsigned*)hsrc;
    float ax, ay;
    gather_row(h2, col, rowptr[row], degi[row], lane, ax, ay);
    unsigned hv = h2[(size_t)row * 64 + lane];
    float w = inv1[row];
    float hnx = w * (ax + bflo(hv));
    float hny = w * (ay + bfhi(hv));
    if (!final_hop) {
        unsigned o = ((unsigned)f2bf(hnx)) | (((unsigned)f2bf(hny)) << 16);
        ((unsigned*)hnext)[(size_t)row * 64 + lane] = o;
    } else {
        unsigned xu = ((const unsigned*)xb)[(size_t)row * 64 + lane];
        unsigned h1u = ((const unsigned*)h1b)[(size_t)row * 64 + lane];
        float2 e;
        e.x = 0.25f * (bflo(xu) + bflo(h1u) + bflo(hv) + hnx);
        e.y = 0.25f * (bfhi(xu) + bfhi(h1u) + bfhi(hv) + hny);
        ((float2*)outp)[(size_t)row * 64 + lane] = e;
    }
}

// tail: raw row-sum S (fp32)
__global__ __launch_bounds__(256) void k_agg_tail(
    const unsigned short* __restrict__ hsrc, float* __restrict__ S,
    const int* __restrict__ rowptr, const int* __restrict__ degi,
    const int* __restrict__ col)
{
    int row = (blockIdx.x * 256 + threadIdx.x) >> 6;
    if (row >= N_NODES) return;
    int lane = threadIdx.x & 63;
    float ax, ay;
    gather_row((const unsigned*)hsrc, col, rowptr[row], degi[row], lane, ax, ay);
    float2 o; o.x = ax; o.y = ay;
    ((float2*)S)[(size_t)row * 64 + lane] = o;
}

// ---------------- tail GEMM + update (MFMA bf16 16x16x32), 16 rows/wave ----------------
// Z = [h | inv0*S] @ Wl  (N x 256).  gamma=lrelu(Z1)+1, beta=lrelu(Z2)
// m = h + gamma*R + beta - inv0*S;  h_new = inv2*(S + h + m)
// non-last: write h_new (bf16). last: emb = 0.25*(x+h1+h2+h_new) -> out rows with deg<=5.
__global__ __launch_bounds__(256) void k_gemm_tail(
    const unsigned short* __restrict__ hb, const float* __restrict__ S,
    unsigned short* __restrict__ hb_next,
    const unsigned short* __restrict__ xb, const unsigned short* __restrict__ h1b,
    float* __restrict__ outp,
    const float* __restrict__ Rl, const short* __restrict__ Wp,
    const float* __restrict__ inv0, const float* __restrict__ inv2,
    const int* __restrict__ degi, int last)
{
    __shared__ __align__(16) float zb[4][8][264];
    int wave = threadIdx.x >> 6, lane = threadIdx.x & 63;
    int quad = lane >> 4, m16 = lane & 15;
    int r0 = blockIdx.x * 64 + wave * 16;
    int rowA = r0 + m16;
    int cA = rowA < N_NODES ? rowA : N_NODES - 1;
    float w0 = inv0[cA];
    const unsigned short* hrow = hb + (size_t)cA * DIM;
    const float* srow = S + (size_t)cA * DIM;

    f32x4 acc[16];
    const f32x4 vz = {0.f, 0.f, 0.f, 0.f};
#pragma unroll
    for (int t = 0; t < 16; ++t) acc[t] = vz;

#pragma unroll
    for (int kb = 0; kb < 8; ++kb) {
        bf16x8 a;
        if (kb < 4) {
            a = *(const bf16x8*)(hrow + kb * 32 + quad * 8);
        } else {
            const float* sp = srow + (kb - 4) * 32 + quad * 8;
            f32x4 u0 = *(const f32x4*)sp;
            f32x4 u1 = *(const f32x4*)(sp + 4);
#pragma unroll
            for (int j = 0; j < 4; ++j) {
                a[j]     = (short)f2bf(w0 * u0[j]);
                a[4 + j] = (short)f2bf(w0 * u1[j]);
            }
        }
        const short* wb = Wp + kb * 8192 + lane * 8;
#pragma unroll
        for (int nt = 0; nt < 16; ++nt) {
            bf16x8 b = *(const bf16x8*)(wb + nt * 512);
            acc[nt] = __builtin_amdgcn_mfma_f32_16x16x32_bf16(a, b, acc[nt], 0, 0, 0);
        }
    }

    // epilogue: C/D layout col = lane&15 (-> n), row = quad*4+reg (-> node)
    // stage 8 rows at a time through per-wave LDS, then fully coalesced compute/store
    int c4 = (lane & 31) * 4;
    int halfsel = lane >> 5;
    f32x4 Rv = *(const f32x4*)(Rl + c4);

#pragma unroll
    for (int s = 0; s < 2; ++s) {
        if ((quad >> 1) == s) {
            int lr = (quad & 1) * 4;
#pragma unroll
            for (int nt = 0; nt < 16; ++nt)
#pragma unroll
                for (int r = 0; r < 4; ++r)
                    zb[wave][lr + r][nt * 16 + m16] = acc[nt][r];
        }
        __syncthreads();
#pragma unroll
        for (int it = 0; it < 4; ++it) {
            int lr = it * 2 + halfsel;
            int gi = r0 + s * 8 + lr;
            if (gi < N_NODES) {
                f32x4 z1 = *(const f32x4*)&zb[wave][lr][c4];
                f32x4 z2 = *(const f32x4*)&zb[wave][lr][128 + c4];
                u16x4 hu = *(const u16x4*)(hb + (size_t)gi * DIM + c4);
                f32x4 sv = *(const f32x4*)(S + (size_t)gi * DIM + c4);
                float wi0 = inv0[gi], wi2 = inv2[gi];
                f32x4 hn, hvf;
#pragma unroll
                for (int j = 0; j < 4; ++j) {
                    float h = bf2f(hu[j]);
                    float sva = sv[j];
                    float nb = wi0 * sva;
                    float g = (z1[j] > 0.f ? z1[j] : 0.2f * z1[j]) + 1.0f;
                    float be = (z2[j] > 0.f ? z2[j] : 0.2f * z2[j]);
                    float mm = h + g * Rv[j] + be - nb;
                    hn[j] = wi2 * (sva + h + mm);
                    hvf[j] = h;
                }
                if (!last) {
                    u16x4 o;
#pragma unroll
                    for (int j = 0; j < 4; ++j) o[j] = f2bf(hn[j]);
                    *(u16x4*)(hb_next + (size_t)gi * DIM + c4) = o;
                } else if (degi[gi] <= 5) {
                    u16x4 xu  = *(const u16x4*)(xb  + (size_t)gi * DIM + c4);
                    u16x4 h1u = *(const u16x4*)(h1b + (size_t)gi * DIM + c4);
                    f32x4 ev;
#pragma unroll
                    for (int j = 0; j < 4; ++j)
                        ev[j] = 0.25f * (bf2f(xu[j]) + bf2f(h1u[j]) + hvf[j] + hn[j]);
                    *(f32x4*)(outp + (size_t)gi * DIM + c4) = ev;
                }
            }
        }
        __syncthreads();
    }
}

// ---------------- launch ----------------

extern "C" void kernel_launch(void* const* d_in, const int* in_sizes, int n_in,
                              void* d_out, int out_size, void* d_ws, size_t ws_size,
                              hipStream_t stream) {
    const float* x  = (const float*)d_in[0];
    const float* G1 = (const float*)d_in[1];
    const float* G2 = (const float*)d_in[2];
    const float* B1 = (const float*)d_in[3];
    const float* B2 = (const float*)d_in[4];
    const float* R  = (const float*)d_in[5];
    const int* esrc = (const int*)d_in[6];
    const int* edst = (const int*)d_in[7];
    float* out = (float*)d_out;

    char* base = (char*)d_ws;
    size_t off = 0;
    auto alloc = [&](size_t b) -> void* {
        void* p = base + off;
        off = (off + b + 255) & ~(size_t)255;
        return p;
    };
    int* degi   = (int*)alloc(4 * N_NODES);
    int* rowptr = (int*)alloc(4 * N_NODES);
    int* cnt    = (int*)alloc(4 * N_NODES);
    int* bsum   = (int*)alloc(4 * 256);
    int* col    = (int*)alloc(4 * N_EDGES);
    float* inv0 = (float*)alloc(4 * N_NODES);
    float* inv1 = (float*)alloc(4 * N_NODES);
    float* inv2 = (float*)alloc(4 * N_NODES);
    short* Wp   = (short*)alloc(2 * 3 * 65536);
    unsigned short* xb = (unsigned short*)alloc(2ull * N_NODES * DIM);
    unsigned short* hA = (unsigned short*)alloc(2ull * N_NODES * DIM);
    unsigned short* hB = (unsigned short*)alloc(2ull * N_NODES * DIM);
    float* S    = (float*)alloc(4ull * N_NODES * DIM);

    hipMemsetAsync(degi, 0, 4 * N_NODES, stream);
    k_degree<<<(N_EDGES + 255) / 256, 256, 0, stream>>>(esrc, degi);
    k_chunksum<<<NCHUNK, SCAN_B, 0, stream>>>(degi, bsum);
    k_scanb<<<1, 128, 0, stream>>>(bsum, NCHUNK);
    k_rowptr<<<NCHUNK, SCAN_B, 0, stream>>>(degi, bsum, rowptr, cnt, inv0, inv1, inv2);
    k_fill<<<(N_EDGES + 255) / 256, 256, 0, stream>>>(esrc, edst, cnt, col);
    k_pack<<<768, 256, 0, stream>>>(G1, G2, B1, B2, Wp);
    k_xcast<<<12500, 256, 0, stream>>>(x, xb);

    // ---- head pass: h1->hA, h2->hB, final computes emb -> out (all rows) ----
    k_agg_head<<<25000, 256, 0, stream>>>(xb, hA, xb, hA, out, inv1, rowptr, degi, col, 0);
    k_agg_head<<<25000, 256, 0, stream>>>(hA, hB, xb, hA, out, inv1, rowptr, degi, col, 0);
    k_agg_head<<<25000, 256, 0, stream>>>(hB, hB, xb, hA, out, inv1, rowptr, degi, col, 1);

    // ---- tail pass: agg -> GEMM+update per hop (h1->hA, h2->hB) ----
    k_agg_tail<<<25000, 256, 0, stream>>>(xb, S, rowptr, degi, col);
    k_gemm_tail<<<1563, 256, 0, stream>>>(xb, S, hA, xb, hA, out, R,       Wp,          inv0, inv2, degi, 0);
    k_agg_tail<<<25000, 256, 0, stream>>>(hA, S, rowptr, degi, col);
    k_gemm_tail<<<1563, 256, 0, stream>>>(hA, S, hB, xb, hA, out, R + 128, Wp + 65536,  inv0, inv2, degi, 0);
    k_agg_tail<<<25000, 256, 0, stream>>>(hB, S, rowptr, degi, col);
    k_gemm_tail<<<1563, 256, 0, stream>>>(hB, S, hB, xb, hA, out, R + 256, Wp + 131072, inv0, inv2, degi, 1);
}

// Round 4
// 543.039 us; speedup vs baseline: 2.1800x; 1.1032x over previous
//
#include <hip/hip_runtime.h>

#define N_NODES 100000
#define N_EDGES 600000
#define DIM 128
#define SCAN_B 1024
#define NCHUNK 98   // ceil(100000/1024)

typedef __attribute__((ext_vector_type(4))) float f32x4;
typedef __attribute__((ext_vector_type(8))) short bf16x8;
typedef __attribute__((ext_vector_type(4))) unsigned short u16x4;
typedef __attribute__((ext_vector_type(8))) unsigned short u16x8;

__device__ __forceinline__ unsigned short f2bf(float f) {
    union { float f; unsigned u; } cv; cv.f = f;
    unsigned r = (cv.u + 0x7FFFu + ((cv.u >> 16) & 1u)) >> 16;
    return (unsigned short)r;
}
__device__ __forceinline__ float bf2f(unsigned short v) {
    union { unsigned u; float f; } c; c.u = ((unsigned)v) << 16; return c.f;
}
__device__ __forceinline__ float bflo(unsigned v) {
    union { unsigned u; float f; } c; c.u = v << 16; return c.f;
}
__device__ __forceinline__ float bfhi(unsigned v) {
    union { unsigned u; float f; } c; c.u = v & 0xFFFF0000u; return c.f;
}

// ---------------- setup: degree / scan / csr fill / weight pack ----------------

__global__ void k_degree(const int* __restrict__ src, int* __restrict__ degi) {
    int e = blockIdx.x * 256 + threadIdx.x;
    if (e < N_EDGES) atomicAdd(&degi[src[e]], 1);
}

__global__ void k_chunksum(const int* __restrict__ degi, int* __restrict__ bsum) {
    __shared__ int sm[SCAN_B];
    int i = blockIdx.x * SCAN_B + threadIdx.x;
    sm[threadIdx.x] = (i < N_NODES) ? degi[i] : 0;
    __syncthreads();
    for (int s = SCAN_B / 2; s > 0; s >>= 1) {
        if (threadIdx.x < (unsigned)s) sm[threadIdx.x] += sm[threadIdx.x + s];
        __syncthreads();
    }
    if (threadIdx.x == 0) bsum[blockIdx.x] = sm[0];
}

__global__ void k_scanb(int* __restrict__ bsum, int nb) {
    __shared__ int sm[128];
    int t = threadIdx.x;
    int v = (t < nb) ? bsum[t] : 0;
    sm[t] = v; __syncthreads();
    for (int s = 1; s < 128; s <<= 1) {
        int a = (t >= s) ? sm[t - s] : 0;
        __syncthreads();
        sm[t] += a;
        __syncthreads();
    }
    if (t < nb) bsum[t] = sm[t] - v;  // exclusive
}

__global__ void k_rowptr(const int* __restrict__ degi, const int* __restrict__ bsum,
                         int* __restrict__ rowptr, int* __restrict__ cnt,
                         float* __restrict__ inv0, float* __restrict__ inv1,
                         float* __restrict__ inv2) {
    __shared__ int sm[SCAN_B];
    int i = blockIdx.x * SCAN_B + threadIdx.x;
    int v = (i < N_NODES) ? degi[i] : 0;
    sm[threadIdx.x] = v; __syncthreads();
    for (int s = 1; s < SCAN_B; s <<= 1) {
        int a = (threadIdx.x >= (unsigned)s) ? sm[threadIdx.x - s] : 0;
        __syncthreads();
        sm[threadIdx.x] += a;
        __syncthreads();
    }
    if (i < N_NODES) {
        int excl = bsum[blockIdx.x] + sm[threadIdx.x] - v;
        rowptr[i] = excl;
        cnt[i] = excl;
        float d = (float)v;
        inv0[i] = (v > 0) ? 1.0f / d : 0.0f;
        inv1[i] = 1.0f / (d + 1.0f);
        inv2[i] = 1.0f / (d + 2.0f);
    }
}

__global__ void k_fill(const int* __restrict__ src, const int* __restrict__ dst,
                       int* __restrict__ cnt, int* __restrict__ col) {
    int e = blockIdx.x * 256 + threadIdx.x;
    if (e < N_EDGES) {
        int pos = atomicAdd(&cnt[src[e]], 1);
        col[pos] = dst[e];
    }
}

// Wpack[l][kb(8)][nt(16)][lane(64)][j(8)]  = W[k][n], k=kb*32+(lane>>4)*8+j, n=nt*16+(lane&15)
__global__ void k_pack(const float* __restrict__ G1, const float* __restrict__ G2,
                       const float* __restrict__ B1, const float* __restrict__ B2,
                       short* __restrict__ Wp) {
    int idx = blockIdx.x * 256 + threadIdx.x;  // 3*65536 = 196608 total
    int j = idx & 7, lane = (idx >> 3) & 63, nt = (idx >> 9) & 15, kb = (idx >> 13) & 7, l = idx >> 16;
    int k = kb * 32 + (lane >> 4) * 8 + j;
    int n = nt * 16 + (lane & 15);
    float v;
    if (n < 128) {
        v = (k < 128) ? G1[(l * 128 + n) * 128 + k] : G2[(l * 128 + n) * 128 + (k - 128)];
    } else {
        int n2 = n - 128;
        v = (k < 128) ? B1[(l * 128 + n2) * 128 + k] : B2[(l * 128 + n2) * 128 + (k - 128)];
    }
    Wp[idx] = (short)f2bf(v);
}

__global__ void k_xcast(const float* __restrict__ x, unsigned short* __restrict__ xb) {
    int i = (blockIdx.x * 256 + threadIdx.x) * 4;
    f32x4 v = *(const f32x4*)(x + i);
    unsigned short o0 = f2bf(v[0]), o1 = f2bf(v[1]), o2 = f2bf(v[2]), o3 = f2bf(v[3]);
    unsigned long long pk = (unsigned long long)o0 | ((unsigned long long)o1 << 16)
                          | ((unsigned long long)o2 << 32) | ((unsigned long long)o3 << 48);
    *(unsigned long long*)(xb + i) = pk;
}

// ---------------- gather: 4 rows per wave, 16B loads, shfl-broadcast cols ----------------
// lane = g*16 + c: sub-row g = lane>>4 handles row wid*4+g; c indexes 8-bf16 (16B) chunks.

__device__ __forceinline__ void gather4(const u16x8* __restrict__ h8,
        const int* __restrict__ col, int start, int d, int lane, float* acc) {
    int c = lane & 15;
    int base = lane & 48;
    int dd = d < 16 ? d : 16;
    int idx = (c < dd) ? col[start + c] : 0;
    int dm = d;
    int tmx = __shfl_xor(dm, 16);
    dm = dm > tmx ? dm : tmx;
    tmx = __shfl_xor(dm, 32);
    dm = dm > tmx ? dm : tmx;          // wave-uniform max degree of the 4 rows
    int dmain = dm < 16 ? dm : 16;
    int e = 0;
    for (; e + 2 <= dmain; e += 2) {
        int c0 = __shfl(idx, base + e, 64);
        int c1 = __shfl(idx, base + e + 1, 64);
        if (e < d) {
            u16x8 v = h8[(size_t)c0 * 16 + c];
#pragma unroll
            for (int j = 0; j < 8; ++j) acc[j] += bf2f(v[j]);
        }
        if (e + 1 < d) {
            u16x8 v = h8[(size_t)c1 * 16 + c];
#pragma unroll
            for (int j = 0; j < 8; ++j) acc[j] += bf2f(v[j]);
        }
    }
    if (e < dmain) {
        int c0 = __shfl(idx, base + e, 64);
        if (e < d) {
            u16x8 v = h8[(size_t)c0 * 16 + c];
#pragma unroll
            for (int j = 0; j < 8; ++j) acc[j] += bf2f(v[j]);
        }
        ++e;
    }
    if (dm > 16) {  // cold path: deg > 16 (~handful of rows)
        for (; e < d; ++e) {
            int c0 = col[start + e];
            u16x8 v = h8[(size_t)c0 * 16 + c];
#pragma unroll
            for (int j = 0; j < 8; ++j) acc[j] += bf2f(v[j]);
        }
    }
}

// shared hop-0: raw sums S(x) -> S (fp32) AND head h1 = inv1*(S+x) -> hA (bf16)
__global__ __launch_bounds__(256) void k_agg0(
    const unsigned short* __restrict__ xb, float* __restrict__ S,
    unsigned short* __restrict__ hA, const float* __restrict__ inv1,
    const int* __restrict__ rowptr, const int* __restrict__ degi,
    const int* __restrict__ col)
{
    int lane = threadIdx.x & 63;
    int wid = (blockIdx.x * 256 + threadIdx.x) >> 6;
    int g = lane >> 4, c = lane & 15;
    int row = wid * 4 + g;              // grid exact: 6250*4*4 = 100000
    int start = rowptr[row], d = degi[row];
    float acc[8] = {0,0,0,0,0,0,0,0};
    gather4((const u16x8*)xb, col, start, d, lane, acc);
    u16x8 hv = ((const u16x8*)xb)[(size_t)row * 16 + c];
    float w = inv1[row];
    f32x4 s0, s1;
    u16x8 ho;
#pragma unroll
    for (int j = 0; j < 4; ++j) { s0[j] = acc[j]; s1[j] = acc[4 + j]; }
#pragma unroll
    for (int j = 0; j < 8; ++j) ho[j] = f2bf(w * (acc[j] + bf2f(hv[j])));
    float* sp = S + (size_t)row * DIM + c * 8;
    *(f32x4*)sp = s0;
    *(f32x4*)(sp + 4) = s1;
    ((u16x8*)hA)[(size_t)row * 16 + c] = ho;
}

// head hops 1,2: h_next = inv1*(S+h); final hop emits emb = 0.25*(x+h1+h2+h3) -> out (ALL rows)
__global__ __launch_bounds__(256) void k_agg_head4(
    const unsigned short* __restrict__ hsrc, unsigned short* __restrict__ hnext,
    const unsigned short* __restrict__ xb, const unsigned short* __restrict__ h1b,
    float* __restrict__ outp, const float* __restrict__ inv1,
    const int* __restrict__ rowptr, const int* __restrict__ degi,
    const int* __restrict__ col, int final_hop)
{
    int lane = threadIdx.x & 63;
    int wid = (blockIdx.x * 256 + threadIdx.x) >> 6;
    int g = lane >> 4, c = lane & 15;
    int row = wid * 4 + g;
    int start = rowptr[row], d = degi[row];
    float acc[8] = {0,0,0,0,0,0,0,0};
    gather4((const u16x8*)hsrc, col, start, d, lane, acc);
    u16x8 hv = ((const u16x8*)hsrc)[(size_t)row * 16 + c];
    float w = inv1[row];
    float hn[8];
#pragma unroll
    for (int j = 0; j < 8; ++j) hn[j] = w * (acc[j] + bf2f(hv[j]));
    if (!final_hop) {
        u16x8 ho;
#pragma unroll
        for (int j = 0; j < 8; ++j) ho[j] = f2bf(hn[j]);
        ((u16x8*)hnext)[(size_t)row * 16 + c] = ho;
    } else {
        u16x8 xv = ((const u16x8*)xb)[(size_t)row * 16 + c];
        u16x8 h1 = ((const u16x8*)h1b)[(size_t)row * 16 + c];
        f32x4 e0, e1;
#pragma unroll
        for (int j = 0; j < 4; ++j)
            e0[j] = 0.25f * (bf2f(xv[j]) + bf2f(h1[j]) + bf2f(hv[j]) + hn[j]);
#pragma unroll
        for (int j = 0; j < 4; ++j)
            e1[j] = 0.25f * (bf2f(xv[4 + j]) + bf2f(h1[4 + j]) + bf2f(hv[4 + j]) + hn[4 + j]);
        float* op = outp + (size_t)row * DIM + c * 8;
        *(f32x4*)op = e0;
        *(f32x4*)(op + 4) = e1;
    }
}

// tail agg: raw row-sum -> S (fp32)
__global__ __launch_bounds__(256) void k_agg_tail4(
    const unsigned short* __restrict__ hsrc, float* __restrict__ S,
    const int* __restrict__ rowptr, const int* __restrict__ degi,
    const int* __restrict__ col)
{
    int lane = threadIdx.x & 63;
    int wid = (blockIdx.x * 256 + threadIdx.x) >> 6;
    int g = lane >> 4, c = lane & 15;
    int row = wid * 4 + g;
    int start = rowptr[row], d = degi[row];
    float acc[8] = {0,0,0,0,0,0,0,0};
    gather4((const u16x8*)hsrc, col, start, d, lane, acc);
    f32x4 s0, s1;
#pragma unroll
    for (int j = 0; j < 4; ++j) { s0[j] = acc[j]; s1[j] = acc[4 + j]; }
    float* sp = S + (size_t)row * DIM + c * 8;
    *(f32x4*)sp = s0;
    *(f32x4*)(sp + 4) = s1;
}

// ---------------- tail GEMM + update (R2-verbatim known-good kernel) ----------------
// Z = [h | inv0*S] @ Wl  (N x 256).  gamma=lrelu(Z1)+1, beta=lrelu(Z2)
// m = h + gamma*R + beta - inv0*S;  h_new = inv2*(S + h + m)
// non-last: write h_new (bf16). last: emb = 0.25*(x+t1+t2+t_new) -> out rows with deg<=5.
__global__ __launch_bounds__(256) void k_gemm_tail(
    const unsigned short* __restrict__ hb, const float* __restrict__ S,
    unsigned short* __restrict__ hb_next,
    const unsigned short* __restrict__ xb, const unsigned short* __restrict__ h1b,
    float* __restrict__ outp,
    const float* __restrict__ Rl, const short* __restrict__ Wp,
    const float* __restrict__ inv0, const float* __restrict__ inv2,
    const int* __restrict__ degi, int last)
{
    __shared__ __align__(16) float zb[4][8][264];
    int wave = threadIdx.x >> 6, lane = threadIdx.x & 63;
    int quad = lane >> 4, m16 = lane & 15;
    int r0 = blockIdx.x * 64 + wave * 16;
    int rowA = r0 + m16;
    int cA = rowA < N_NODES ? rowA : N_NODES - 1;
    float w0 = inv0[cA];
    const unsigned short* hrow = hb + (size_t)cA * DIM;
    const float* srow = S + (size_t)cA * DIM;

    f32x4 acc[16];
    const f32x4 vz = {0.f, 0.f, 0.f, 0.f};
#pragma unroll
    for (int t = 0; t < 16; ++t) acc[t] = vz;

#pragma unroll
    for (int kb = 0; kb < 8; ++kb) {
        bf16x8 a;
        if (kb < 4) {
            a = *(const bf16x8*)(hrow + kb * 32 + quad * 8);
        } else {
            const float* sp = srow + (kb - 4) * 32 + quad * 8;
            f32x4 u0 = *(const f32x4*)sp;
            f32x4 u1 = *(const f32x4*)(sp + 4);
#pragma unroll
            for (int j = 0; j < 4; ++j) {
                a[j]     = (short)f2bf(w0 * u0[j]);
                a[4 + j] = (short)f2bf(w0 * u1[j]);
            }
        }
        const short* wb = Wp + kb * 8192 + lane * 8;
#pragma unroll
        for (int nt = 0; nt < 16; ++nt) {
            bf16x8 b = *(const bf16x8*)(wb + nt * 512);
            acc[nt] = __builtin_amdgcn_mfma_f32_16x16x32_bf16(a, b, acc[nt], 0, 0, 0);
        }
    }

    // epilogue: C/D layout col = lane&15 (-> n), row = quad*4+r (-> node)
    int c4 = (lane & 31) * 4;
    int halfsel = lane >> 5;
    f32x4 Rv = *(const f32x4*)(Rl + c4);

#pragma unroll
    for (int s = 0; s < 2; ++s) {
        if ((quad >> 1) == s) {
            int lr = (quad & 1) * 4;
#pragma unroll
            for (int nt = 0; nt < 16; ++nt)
#pragma unroll
                for (int r = 0; r < 4; ++r)
                    zb[wave][lr + r][nt * 16 + m16] = acc[nt][r];
        }
        __syncthreads();
#pragma unroll
        for (int it = 0; it < 4; ++it) {
            int lr = it * 2 + halfsel;
            int gi = r0 + s * 8 + lr;
            if (gi < N_NODES) {
                f32x4 z1 = *(const f32x4*)&zb[wave][lr][c4];
                f32x4 z2 = *(const f32x4*)&zb[wave][lr][128 + c4];
                u16x4 hu = *(const u16x4*)(hb + (size_t)gi * DIM + c4);
                f32x4 sv = *(const f32x4*)(S + (size_t)gi * DIM + c4);
                float wi0 = inv0[gi], wi2 = inv2[gi];
                f32x4 hn, hvf;
#pragma unroll
                for (int j = 0; j < 4; ++j) {
                    float h = bf2f(hu[j]);
                    float sva = sv[j];
                    float nb = wi0 * sva;
                    float g = (z1[j] > 0.f ? z1[j] : 0.2f * z1[j]) + 1.0f;
                    float be = (z2[j] > 0.f ? z2[j] : 0.2f * z2[j]);
                    float mm = h + g * Rv[j] + be - nb;
                    hn[j] = wi2 * (sva + h + mm);
                    hvf[j] = h;
                }
                if (!last) {
                    u16x4 o;
#pragma unroll
                    for (int j = 0; j < 4; ++j) o[j] = f2bf(hn[j]);
                    *(u16x4*)(hb_next + (size_t)gi * DIM + c4) = o;
                } else if (degi[gi] <= 5) {
                    u16x4 xu  = *(const u16x4*)(xb  + (size_t)gi * DIM + c4);
                    u16x4 h1u = *(const u16x4*)(h1b + (size_t)gi * DIM + c4);
                    f32x4 ev;
#pragma unroll
                    for (int j = 0; j < 4; ++j)
                        ev[j] = 0.25f * (bf2f(xu[j]) + bf2f(h1u[j]) + hvf[j] + hn[j]);
                    *(f32x4*)(outp + (size_t)gi * DIM + c4) = ev;
                }
            }
        }
        __syncthreads();
    }
}

// ---------------- launch ----------------

extern "C" void kernel_launch(void* const* d_in, const int* in_sizes, int n_in,
                              void* d_out, int out_size, void* d_ws, size_t ws_size,
                              hipStream_t stream) {
    const float* x  = (const float*)d_in[0];
    const float* G1 = (const float*)d_in[1];
    const float* G2 = (const float*)d_in[2];
    const float* B1 = (const float*)d_in[3];
    const float* B2 = (const float*)d_in[4];
    const float* R  = (const float*)d_in[5];
    const int* esrc = (const int*)d_in[6];
    const int* edst = (const int*)d_in[7];
    float* out = (float*)d_out;

    char* base = (char*)d_ws;
    size_t off = 0;
    auto alloc = [&](size_t b) -> void* {
        void* p = base + off;
        off = (off + b + 255) & ~(size_t)255;
        return p;
    };
    int* degi   = (int*)alloc(4 * N_NODES);
    int* rowptr = (int*)alloc(4 * N_NODES);
    int* cnt    = (int*)alloc(4 * N_NODES);
    int* bsum   = (int*)alloc(4 * 256);
    int* col    = (int*)alloc(4 * N_EDGES);
    float* inv0 = (float*)alloc(4 * N_NODES);
    float* inv1 = (float*)alloc(4 * N_NODES);
    float* inv2 = (float*)alloc(4 * N_NODES);
    short* Wp   = (short*)alloc(2 * 3 * 65536);
    unsigned short* xb = (unsigned short*)alloc(2ull * N_NODES * DIM);
    unsigned short* hA = (unsigned short*)alloc(2ull * N_NODES * DIM);  // head h1
    unsigned short* hB = (unsigned short*)alloc(2ull * N_NODES * DIM);  // head h2, then tail t2
    unsigned short* tA = (unsigned short*)alloc(2ull * N_NODES * DIM);  // tail t1
    float* S    = (float*)alloc(4ull * N_NODES * DIM);                  // fp32 row sums

    hipMemsetAsync(degi, 0, 4 * N_NODES, stream);
    k_degree<<<(N_EDGES + 255) / 256, 256, 0, stream>>>(esrc, degi);
    k_chunksum<<<NCHUNK, SCAN_B, 0, stream>>>(degi, bsum);
    k_scanb<<<1, 128, 0, stream>>>(bsum, NCHUNK);
    k_rowptr<<<NCHUNK, SCAN_B, 0, stream>>>(degi, bsum, rowptr, cnt, inv0, inv1, inv2);
    k_fill<<<(N_EDGES + 255) / 256, 256, 0, stream>>>(esrc, edst, cnt, col);
    k_pack<<<768, 256, 0, stream>>>(G1, G2, B1, B2, Wp);
    k_xcast<<<12500, 256, 0, stream>>>(x, xb);

    // shared hop 0: fp32 S(x) for tail gemm0 + head h1
    k_agg0<<<6250, 256, 0, stream>>>(xb, S, hA, inv1, rowptr, degi, col);
    k_gemm_tail<<<1563, 256, 0, stream>>>(xb, S, tA, xb, tA, out, R, Wp, inv0, inv2, degi, 0);

    // head hops 1,2 (final writes emb for ALL rows)
    k_agg_head4<<<6250, 256, 0, stream>>>(hA, hB, xb, hA, out, inv1, rowptr, degi, col, 0);
    k_agg_head4<<<6250, 256, 0, stream>>>(hB, hB, xb, hA, out, inv1, rowptr, degi, col, 1);

    // tail hops 1,2 (hB reused as t2; final overwrites deg<=5 rows)
    k_agg_tail4<<<6250, 256, 0, stream>>>(tA, S, rowptr, degi, col);
    k_gemm_tail<<<1563, 256, 0, stream>>>(tA, S, hB, xb, tA, out, R + 128, Wp + 65536, inv0, inv2, degi, 0);
    k_agg_tail4<<<6250, 256, 0, stream>>>(hB, S, rowptr, degi, col);
    k_gemm_tail<<<1563, 256, 0, stream>>>(hB, S, hB, xb, tA, out, R + 256, Wp + 131072, inv0, inv2, degi, 1);
}

// Round 5
// 481.367 us; speedup vs baseline: 2.4593x; 1.1281x over previous
//
#include <hip/hip_runtime.h>

#define N_NODES 100000
#define N_EDGES 600000
#define DIM 128
#define SCAN_B 1024
#define NCHUNK 98   // ceil(100000/1024)

typedef __attribute__((ext_vector_type(4))) float f32x4;
typedef __attribute__((ext_vector_type(8))) short bf16x8;
typedef __attribute__((ext_vector_type(4))) unsigned short u16x4;
typedef __attribute__((ext_vector_type(8))) unsigned short u16x8;

__device__ __forceinline__ unsigned short f2bf(float f) {
    union { float f; unsigned u; } cv; cv.f = f;
    unsigned r = (cv.u + 0x7FFFu + ((cv.u >> 16) & 1u)) >> 16;
    return (unsigned short)r;
}
__device__ __forceinline__ float bf2f(unsigned short v) {
    union { unsigned u; float f; } c; c.u = ((unsigned)v) << 16; return c.f;
}

// ---------------- setup: degree / scan / csr fill / weight pack ----------------

__global__ void k_degree(const int* __restrict__ src, int* __restrict__ degi) {
    int e = blockIdx.x * 256 + threadIdx.x;
    if (e < N_EDGES) atomicAdd(&degi[src[e]], 1);
}

__global__ void k_chunksum(const int* __restrict__ degi, int* __restrict__ bsum) {
    __shared__ int sm[SCAN_B];
    int i = blockIdx.x * SCAN_B + threadIdx.x;
    sm[threadIdx.x] = (i < N_NODES) ? degi[i] : 0;
    __syncthreads();
    for (int s = SCAN_B / 2; s > 0; s >>= 1) {
        if (threadIdx.x < (unsigned)s) sm[threadIdx.x] += sm[threadIdx.x + s];
        __syncthreads();
    }
    if (threadIdx.x == 0) bsum[blockIdx.x] = sm[0];
}

__global__ void k_scanb(int* __restrict__ bsum, int nb) {
    __shared__ int sm[128];
    int t = threadIdx.x;
    int v = (t < nb) ? bsum[t] : 0;
    sm[t] = v; __syncthreads();
    for (int s = 1; s < 128; s <<= 1) {
        int a = (t >= s) ? sm[t - s] : 0;
        __syncthreads();
        sm[t] += a;
        __syncthreads();
    }
    if (t < nb) bsum[t] = sm[t] - v;  // exclusive
}

__global__ void k_rowptr(const int* __restrict__ degi, const int* __restrict__ bsum,
                         int* __restrict__ rowptr, int* __restrict__ cnt,
                         float* __restrict__ inv0, float* __restrict__ inv1,
                         float* __restrict__ inv2) {
    __shared__ int sm[SCAN_B];
    int i = blockIdx.x * SCAN_B + threadIdx.x;
    int v = (i < N_NODES) ? degi[i] : 0;
    sm[threadIdx.x] = v; __syncthreads();
    for (int s = 1; s < SCAN_B; s <<= 1) {
        int a = (threadIdx.x >= (unsigned)s) ? sm[threadIdx.x - s] : 0;
        __syncthreads();
        sm[threadIdx.x] += a;
        __syncthreads();
    }
    if (i < N_NODES) {
        int excl = bsum[blockIdx.x] + sm[threadIdx.x] - v;
        rowptr[i] = excl;
        cnt[i] = excl;
        float d = (float)v;
        inv0[i] = (v > 0) ? 1.0f / d : 0.0f;
        inv1[i] = 1.0f / (d + 1.0f);
        inv2[i] = 1.0f / (d + 2.0f);
    }
}

__global__ void k_fill(const int* __restrict__ src, const int* __restrict__ dst,
                       int* __restrict__ cnt, int* __restrict__ col) {
    int e = blockIdx.x * 256 + threadIdx.x;
    if (e < N_EDGES) {
        int pos = atomicAdd(&cnt[src[e]], 1);
        col[pos] = dst[e];
    }
}

// Wpack[l][kb(8)][nt(16)][lane(64)][j(8)]  = W[k][n], k=kb*32+(lane>>4)*8+j, n=nt*16+(lane&15)
__global__ void k_pack(const float* __restrict__ G1, const float* __restrict__ G2,
                       const float* __restrict__ B1, const float* __restrict__ B2,
                       short* __restrict__ Wp) {
    int idx = blockIdx.x * 256 + threadIdx.x;  // 3*65536 = 196608 total
    int j = idx & 7, lane = (idx >> 3) & 63, nt = (idx >> 9) & 15, kb = (idx >> 13) & 7, l = idx >> 16;
    int k = kb * 32 + (lane >> 4) * 8 + j;
    int n = nt * 16 + (lane & 15);
    float v;
    if (n < 128) {
        v = (k < 128) ? G1[(l * 128 + n) * 128 + k] : G2[(l * 128 + n) * 128 + (k - 128)];
    } else {
        int n2 = n - 128;
        v = (k < 128) ? B1[(l * 128 + n2) * 128 + k] : B2[(l * 128 + n2) * 128 + (k - 128)];
    }
    Wp[idx] = (short)f2bf(v);
}

__global__ void k_xcast(const float* __restrict__ x, unsigned short* __restrict__ xb) {
    int i = (blockIdx.x * 256 + threadIdx.x) * 4;
    f32x4 v = *(const f32x4*)(x + i);
    unsigned short o0 = f2bf(v[0]), o1 = f2bf(v[1]), o2 = f2bf(v[2]), o3 = f2bf(v[3]);
    unsigned long long pk = (unsigned long long)o0 | ((unsigned long long)o1 << 16)
                          | ((unsigned long long)o2 << 32) | ((unsigned long long)o3 << 48);
    *(unsigned long long*)(xb + i) = pk;
}

// ---------------- gather: 4 rows per wave, 16B loads, shfl-broadcast cols ----------------
// lane = g*16 + c: sub-row g = lane>>4 handles row wid*4+g; c indexes 8-bf16 (16B) chunks.

__device__ __forceinline__ void gather4(const u16x8* __restrict__ h8,
        const int* __restrict__ col, int start, int d, int lane, float* acc) {
    int c = lane & 15;
    int base = lane & 48;
    int dd = d < 16 ? d : 16;
    int idx = (c < dd) ? col[start + c] : 0;
    int dm = d;
    int tmx = __shfl_xor(dm, 16);
    dm = dm > tmx ? dm : tmx;
    tmx = __shfl_xor(dm, 32);
    dm = dm > tmx ? dm : tmx;          // wave-uniform max degree of the 4 rows
    int dmain = dm < 16 ? dm : 16;
    int e = 0;
    for (; e + 2 <= dmain; e += 2) {
        int c0 = __shfl(idx, base + e, 64);
        int c1 = __shfl(idx, base + e + 1, 64);
        if (e < d) {
            u16x8 v = h8[(size_t)c0 * 16 + c];
#pragma unroll
            for (int j = 0; j < 8; ++j) acc[j] += bf2f(v[j]);
        }
        if (e + 1 < d) {
            u16x8 v = h8[(size_t)c1 * 16 + c];
#pragma unroll
            for (int j = 0; j < 8; ++j) acc[j] += bf2f(v[j]);
        }
    }
    if (e < dmain) {
        int c0 = __shfl(idx, base + e, 64);
        if (e < d) {
            u16x8 v = h8[(size_t)c0 * 16 + c];
#pragma unroll
            for (int j = 0; j < 8; ++j) acc[j] += bf2f(v[j]);
        }
        ++e;
    }
    if (dm > 16) {  // cold path: deg > 16 (~handful of rows)
        for (; e < d; ++e) {
            int c0 = col[start + e];
            u16x8 v = h8[(size_t)c0 * 16 + c];
#pragma unroll
            for (int j = 0; j < 8; ++j) acc[j] += bf2f(v[j]);
        }
    }
}

// shared hop-0: raw sums S(x) -> Sb (bf16) AND head h1 = inv1*(S+x) -> hA (bf16)
__global__ __launch_bounds__(256) void k_agg0(
    const unsigned short* __restrict__ xb, unsigned short* __restrict__ Sb,
    unsigned short* __restrict__ hA, const float* __restrict__ inv1,
    const int* __restrict__ rowptr, const int* __restrict__ degi,
    const int* __restrict__ col)
{
    int lane = threadIdx.x & 63;
    int wid = (blockIdx.x * 256 + threadIdx.x) >> 6;
    int g = lane >> 4, c = lane & 15;
    int row = wid * 4 + g;              // grid exact: 6250*4*4 = 100000
    int start = rowptr[row], d = degi[row];
    float acc[8] = {0,0,0,0,0,0,0,0};
    gather4((const u16x8*)xb, col, start, d, lane, acc);
    u16x8 hv = ((const u16x8*)xb)[(size_t)row * 16 + c];
    float w = inv1[row];
    u16x8 so, ho;
#pragma unroll
    for (int j = 0; j < 8; ++j) {
        so[j] = f2bf(acc[j]);
        ho[j] = f2bf(w * (acc[j] + bf2f(hv[j])));
    }
    ((u16x8*)Sb)[(size_t)row * 16 + c] = so;
    ((u16x8*)hA)[(size_t)row * 16 + c] = ho;
}

// head hops 1,2: h_next = inv1*(S+h); final hop emits emb = 0.25*(x+h1+h2+h3) -> out (ALL rows)
__global__ __launch_bounds__(256) void k_agg_head4(
    const unsigned short* __restrict__ hsrc, unsigned short* __restrict__ hnext,
    const unsigned short* __restrict__ xb, const unsigned short* __restrict__ h1b,
    float* __restrict__ outp, const float* __restrict__ inv1,
    const int* __restrict__ rowptr, const int* __restrict__ degi,
    const int* __restrict__ col, int final_hop)
{
    int lane = threadIdx.x & 63;
    int wid = (blockIdx.x * 256 + threadIdx.x) >> 6;
    int g = lane >> 4, c = lane & 15;
    int row = wid * 4 + g;
    int start = rowptr[row], d = degi[row];
    float acc[8] = {0,0,0,0,0,0,0,0};
    gather4((const u16x8*)hsrc, col, start, d, lane, acc);
    u16x8 hv = ((const u16x8*)hsrc)[(size_t)row * 16 + c];
    float w = inv1[row];
    float hn[8];
#pragma unroll
    for (int j = 0; j < 8; ++j) hn[j] = w * (acc[j] + bf2f(hv[j]));
    if (!final_hop) {
        u16x8 ho;
#pragma unroll
        for (int j = 0; j < 8; ++j) ho[j] = f2bf(hn[j]);
        ((u16x8*)hnext)[(size_t)row * 16 + c] = ho;
    } else {
        u16x8 xv = ((const u16x8*)xb)[(size_t)row * 16 + c];
        u16x8 h1 = ((const u16x8*)h1b)[(size_t)row * 16 + c];
        f32x4 e0, e1;
#pragma unroll
        for (int j = 0; j < 4; ++j)
            e0[j] = 0.25f * (bf2f(xv[j]) + bf2f(h1[j]) + bf2f(hv[j]) + hn[j]);
#pragma unroll
        for (int j = 0; j < 4; ++j)
            e1[j] = 0.25f * (bf2f(xv[4 + j]) + bf2f(h1[4 + j]) + bf2f(hv[4 + j]) + hn[4 + j]);
        float* op = outp + (size_t)row * DIM + c * 8;
        *(f32x4*)op = e0;
        *(f32x4*)(op + 4) = e1;
    }
}

// tail agg: raw row-sum -> Sb (bf16)
__global__ __launch_bounds__(256) void k_agg_tail4(
    const unsigned short* __restrict__ hsrc, unsigned short* __restrict__ Sb,
    const int* __restrict__ rowptr, const int* __restrict__ degi,
    const int* __restrict__ col)
{
    int lane = threadIdx.x & 63;
    int wid = (blockIdx.x * 256 + threadIdx.x) >> 6;
    int g = lane >> 4, c = lane & 15;
    int row = wid * 4 + g;
    int start = rowptr[row], d = degi[row];
    float acc[8] = {0,0,0,0,0,0,0,0};
    gather4((const u16x8*)hsrc, col, start, d, lane, acc);
    u16x8 so;
#pragma unroll
    for (int j = 0; j < 8; ++j) so[j] = f2bf(acc[j]);
    ((u16x8*)Sb)[(size_t)row * 16 + c] = so;
}

// ---------------- tail GEMM + update: R4 compute structure + LDS-staged B ----------------
// Z = [h | inv0*S] @ Wl  (N x 256).  gamma=lrelu(Z1)+1, beta=lrelu(Z2)
// m = h + gamma*R + beta - inv0*S;  h_new = inv2*(S + h + m)
// non-last: write h_new (bf16). last: emb = 0.25*(x+t1+t2+t_new) -> out rows with deg<=5.
// B (Wp) staged per-kb-slice (16 KB) in double-buffered LDS, shared by all 4 waves.
__global__ __launch_bounds__(256) void k_gemm_tail(
    const unsigned short* __restrict__ hb, const unsigned short* __restrict__ Sb,
    unsigned short* __restrict__ hb_next,
    const unsigned short* __restrict__ xb, const unsigned short* __restrict__ h1b,
    float* __restrict__ outp,
    const float* __restrict__ Rl, const short* __restrict__ Wp,
    const float* __restrict__ inv0, const float* __restrict__ inv2,
    const int* __restrict__ degi, int last)
{
    // LDS: K-loop uses [2][8192] shorts (32 KB B dbuf); epilogue reuses as zb[4][8][264] f32.
    __shared__ __align__(16) char smraw[33792];
    short* smW = (short*)smraw;
    float (*zb)[8][264] = (float(*)[8][264])smraw;

    int wave = threadIdx.x >> 6, lane = threadIdx.x & 63;
    int quad = lane >> 4, m16 = lane & 15;
    int r0 = blockIdx.x * 64 + wave * 16;
    int rowA = r0 + m16;
    int cA = rowA < N_NODES ? rowA : N_NODES - 1;
    float w0 = inv0[cA];
    const unsigned short* hrow = hb + (size_t)cA * DIM;
    const unsigned short* srow = Sb + (size_t)cA * DIM;

    f32x4 acc[16];
    const f32x4 vz = {0.f, 0.f, 0.f, 0.f};
#pragma unroll
    for (int t = 0; t < 16; ++t) acc[t] = vz;

    {   // stage slice kb=0 into buffer 0
        const int4* g = (const int4*)Wp;
        int4* sd = (int4*)smW;
#pragma unroll
        for (int j = 0; j < 4; ++j) sd[j * 256 + threadIdx.x] = g[j * 256 + threadIdx.x];
    }

#pragma unroll
    for (int kb = 0; kb < 8; ++kb) {
        bf16x8 a;
        if (kb < 4) {
            a = *(const bf16x8*)(hrow + kb * 32 + quad * 8);
        } else {
            u16x8 sv = *(const u16x8*)(srow + (kb - 4) * 32 + quad * 8);
#pragma unroll
            for (int j = 0; j < 8; ++j) a[j] = (short)f2bf(w0 * bf2f(sv[j]));
        }
        __syncthreads();   // slice kb staged & visible
        if (kb < 7) {      // stage next slice into the other buffer
            const int4* g = (const int4*)(Wp + (kb + 1) * 8192);
            int4* sd = (int4*)(smW + ((kb + 1) & 1) * 8192);
#pragma unroll
            for (int j = 0; j < 4; ++j) sd[j * 256 + threadIdx.x] = g[j * 256 + threadIdx.x];
        }
        const short* wb = smW + (kb & 1) * 8192 + lane * 8;
#pragma unroll
        for (int nt = 0; nt < 16; ++nt) {
            bf16x8 b = *(const bf16x8*)(wb + nt * 512);
            acc[nt] = __builtin_amdgcn_mfma_f32_16x16x32_bf16(a, b, acc[nt], 0, 0, 0);
        }
    }
    __syncthreads();   // all ds_reads of smW done before LDS reuse as zb

    // epilogue: C/D layout col = lane&15 (-> n), row = quad*4+r (-> node)
    int c4 = (lane & 31) * 4;
    int halfsel = lane >> 5;
    f32x4 Rv = *(const f32x4*)(Rl + c4);

#pragma unroll
    for (int s = 0; s < 2; ++s) {
        if ((quad >> 1) == s) {
            int lr = (quad & 1) * 4;
#pragma unroll
            for (int nt = 0; nt < 16; ++nt)
#pragma unroll
                for (int r = 0; r < 4; ++r)
                    zb[wave][lr + r][nt * 16 + m16] = acc[nt][r];
        }
        __syncthreads();
#pragma unroll
        for (int it = 0; it < 4; ++it) {
            int lr = it * 2 + halfsel;
            int gi = r0 + s * 8 + lr;
            if (gi < N_NODES) {
                f32x4 z1 = *(const f32x4*)&zb[wave][lr][c4];
                f32x4 z2 = *(const f32x4*)&zb[wave][lr][128 + c4];
                u16x4 hu = *(const u16x4*)(hb + (size_t)gi * DIM + c4);
                u16x4 su = *(const u16x4*)(Sb + (size_t)gi * DIM + c4);
                float wi0 = inv0[gi], wi2 = inv2[gi];
                f32x4 hn, hvf;
#pragma unroll
                for (int j = 0; j < 4; ++j) {
                    float h = bf2f(hu[j]);
                    float sva = bf2f(su[j]);
                    float nb = wi0 * sva;
                    float g = (z1[j] > 0.f ? z1[j] : 0.2f * z1[j]) + 1.0f;
                    float be = (z2[j] > 0.f ? z2[j] : 0.2f * z2[j]);
                    float mm = h + g * Rv[j] + be - nb;
                    hn[j] = wi2 * (sva + h + mm);
                    hvf[j] = h;
                }
                if (!last) {
                    u16x4 o;
#pragma unroll
                    for (int j = 0; j < 4; ++j) o[j] = f2bf(hn[j]);
                    *(u16x4*)(hb_next + (size_t)gi * DIM + c4) = o;
                } else if (degi[gi] <= 5) {
                    u16x4 xu  = *(const u16x4*)(xb  + (size_t)gi * DIM + c4);
                    u16x4 h1u = *(const u16x4*)(h1b + (size_t)gi * DIM + c4);
                    f32x4 ev;
#pragma unroll
                    for (int j = 0; j < 4; ++j)
                        ev[j] = 0.25f * (bf2f(xu[j]) + bf2f(h1u[j]) + hvf[j] + hn[j]);
                    *(f32x4*)(outp + (size_t)gi * DIM + c4) = ev;
                }
            }
        }
        __syncthreads();
    }
}

// ---------------- launch ----------------

extern "C" void kernel_launch(void* const* d_in, const int* in_sizes, int n_in,
                              void* d_out, int out_size, void* d_ws, size_t ws_size,
                              hipStream_t stream) {
    const float* x  = (const float*)d_in[0];
    const float* G1 = (const float*)d_in[1];
    const float* G2 = (const float*)d_in[2];
    const float* B1 = (const float*)d_in[3];
    const float* B2 = (const float*)d_in[4];
    const float* R  = (const float*)d_in[5];
    const int* esrc = (const int*)d_in[6];
    const int* edst = (const int*)d_in[7];
    float* out = (float*)d_out;

    char* base = (char*)d_ws;
    size_t off = 0;
    auto alloc = [&](size_t b) -> void* {
        void* p = base + off;
        off = (off + b + 255) & ~(size_t)255;
        return p;
    };
    int* degi   = (int*)alloc(4 * N_NODES);
    int* rowptr = (int*)alloc(4 * N_NODES);
    int* cnt    = (int*)alloc(4 * N_NODES);
    int* bsum   = (int*)alloc(4 * 256);
    int* col    = (int*)alloc(4 * N_EDGES);
    float* inv0 = (float*)alloc(4 * N_NODES);
    float* inv1 = (float*)alloc(4 * N_NODES);
    float* inv2 = (float*)alloc(4 * N_NODES);
    short* Wp   = (short*)alloc(2 * 3 * 65536);
    unsigned short* xb = (unsigned short*)alloc(2ull * N_NODES * DIM);
    unsigned short* hA = (unsigned short*)alloc(2ull * N_NODES * DIM);  // head h1
    unsigned short* hB = (unsigned short*)alloc(2ull * N_NODES * DIM);  // head h2, then tail t2
    unsigned short* tA = (unsigned short*)alloc(2ull * N_NODES * DIM);  // tail t1
    unsigned short* Sb = (unsigned short*)alloc(2ull * N_NODES * DIM);  // bf16 row sums

    hipMemsetAsync(degi, 0, 4 * N_NODES, stream);
    k_degree<<<(N_EDGES + 255) / 256, 256, 0, stream>>>(esrc, degi);
    k_chunksum<<<NCHUNK, SCAN_B, 0, stream>>>(degi, bsum);
    k_scanb<<<1, 128, 0, stream>>>(bsum, NCHUNK);
    k_rowptr<<<NCHUNK, SCAN_B, 0, stream>>>(degi, bsum, rowptr, cnt, inv0, inv1, inv2);
    k_fill<<<(N_EDGES + 255) / 256, 256, 0, stream>>>(esrc, edst, cnt, col);
    k_pack<<<768, 256, 0, stream>>>(G1, G2, B1, B2, Wp);
    k_xcast<<<12500, 256, 0, stream>>>(x, xb);

    // shared hop 0: bf16 S(x) for tail gemm0 + head h1
    k_agg0<<<6250, 256, 0, stream>>>(xb, Sb, hA, inv1, rowptr, degi, col);
    k_gemm_tail<<<1563, 256, 0, stream>>>(xb, Sb, tA, xb, tA, out, R, Wp, inv0, inv2, degi, 0);

    // head hops 1,2 (final writes emb for ALL rows)
    k_agg_head4<<<6250, 256, 0, stream>>>(hA, hB, xb, hA, out, inv1, rowptr, degi, col, 0);
    k_agg_head4<<<6250, 256, 0, stream>>>(hB, hB, xb, hA, out, inv1, rowptr, degi, col, 1);

    // tail hops 1,2 (hB reused as t2; final overwrites deg<=5 rows)
    k_agg_tail4<<<6250, 256, 0, stream>>>(tA, Sb, rowptr, degi, col);
    k_gemm_tail<<<1563, 256, 0, stream>>>(tA, Sb, hB, xb, tA, out, R + 128, Wp + 65536, inv0, inv2, degi, 0);
    k_agg_tail4<<<6250, 256, 0, stream>>>(hB, Sb, rowptr, degi, col);
    k_gemm_tail<<<1563, 256, 0, stream>>>(hB, Sb, hB, xb, tA, out, R + 256, Wp + 131072, inv0, inv2, degi, 1);
}